// Round 28
// baseline (91.107 us; speedup 1.0000x reference)
//
#include <hip/hip_runtime.h>

typedef unsigned long long u64;

#define FSLOTS 16   // per-row sparse column slots
#define RCUT 2048   // speculative scan prefix

// wave-uniform 64-bit broadcast from SGPR lane index b
__device__ __forceinline__ u64 bcast64(u64 v, int b) {
  unsigned lo = __builtin_amdgcn_readlane((unsigned)v, b);
  unsigned hi = __builtin_amdgcn_readlane((unsigned)(v >> 32), b);
  return ((u64)hi << 32) | lo;
}
__device__ __forceinline__ u64 sgpr64(u64 v) {
  unsigned lo = __builtin_amdgcn_readfirstlane((unsigned)v);
  unsigned hi = __builtin_amdgcn_readfirstlane((unsigned)(v >> 32));
  return ((u64)hi << 32) | lo;
}
__device__ __forceinline__ u64 wor64(u64 v) {
#pragma unroll
  for (int off = 32; off; off >>= 1) v |= __shfl_xor(v, off, 64);
  return v;
}

#define APPLYJ(JV, T)                                                      \
  if ((T) < lim_) {                                                        \
    int j_ = (JV);                                                         \
    atomicAnd(&live[j_ >> 6], ~((u64)1 << (j_ & 63)));                     \
  }

#define CHUNK(c, BND, RC, LA, LB, LC, LD)                                  \
  if (out < maxp && (c) < nch) {                                           \
    u64 rem_ = sgpr64(live[(c)]);                                          \
    if (rem_) {                                                            \
      u64 K_;                                                              \
      u64 my_ = ((rem_ >> lane) & 1) ? (BND) : 0;                          \
      u64 A_ = sgpr64(wor64(my_));                                         \
      u64 hot_ = rem_ & A_;                                                \
      if (!hot_) {                                                         \
        K_ = rem_;                                                         \
      } else {                                                             \
        u64 defK_ = rem_ & ~A_;                                            \
        u64 myk_ = ((defK_ >> lane) & 1) ? (BND) : 0;                      \
        u64 S_ = sgpr64(wor64(myk_));                                      \
        K_ = defK_;                                                        \
        while (hot_) {                                                     \
          int b_ = __builtin_amdgcn_readfirstlane(                         \
              (int)__builtin_ctzll(hot_));                                 \
          hot_ &= hot_ - 1;                                                \
          if (!((S_ >> b_) & 1)) {                                         \
            K_ |= (u64)1 << b_;                                            \
            S_ |= bcast64(BND, b_);                                        \
          }                                                                \
        }                                                                  \
      }                                                                    \
      int kc_ = (int)__popcll(K_);                                         \
      bool mine_ = (K_ >> lane) & 1;                                       \
      if (mine_) {                                                         \
        int pos_ = out + (int)__popcll(K_ & (((u64)1 << lane) - 1));       \
        if (pos_ < maxp) sel[pos_] = (c) * 64 + lane;                      \
      }                                                                    \
      out += kc_;                                                          \
      if (kc_ > 0 && out < maxp) {                                         \
        int lim_ = mine_ ? ((RC) < FSLOTS ? (RC) : FSLOTS) : 0;            \
        APPLYJ((LA).x, 0)  APPLYJ((LA).y, 1)                               \
        APPLYJ((LA).z, 2)  APPLYJ((LA).w, 3)                               \
        APPLYJ((LB).x, 4)  APPLYJ((LB).y, 5)                               \
        APPLYJ((LB).z, 6)  APPLYJ((LB).w, 7)                               \
        APPLYJ((LC).x, 8)  APPLYJ((LC).y, 9)                               \
        APPLYJ((LC).z, 10) APPLYJ((LC).w, 11)                              \
        APPLYJ((LD).x, 12) APPLYJ((LD).y, 13)                              \
        APPLYJ((LD).z, 14) APPLYJ((LD).w, 15)                              \
        u64 ovf_ = __ballot(mine_ && (RC) > FSLOTS);                       \
        while (ovf_) {                                                     \
          int l_ = (int)__builtin_ctzll(ovf_);                             \
          ovf_ &= ovf_ - 1;                                                \
          int r_ = (c) * 64 + l_;                                          \
          u64 v0_ = (2 * lane < nch)                                       \
                        ? M[(size_t)r_ * nw + 2 * lane] : 0ULL;            \
          u64 v1_ = (2 * lane + 1 < nch)                                   \
                        ? M[(size_t)r_ * nw + 2 * lane + 1] : 0ULL;        \
          live[2 * lane] &= ~v0_;                                          \
          live[2 * lane + 1] &= ~v1_;                                      \
        }                                                                  \
      }                                                                    \
    }                                                                      \
    {                                                                      \
      int cc_ = (c) + 4;                                                   \
      if (cc_ < nch) {                                                     \
        int r_ = cc_ * 64 + lane;                                          \
        int rr_ = r_ < n ? r_ : n - 1;                                     \
        BND = D1[rr_];                                                     \
        RC = rowcnt[rr_];                                                  \
        const int4* lp_ = (const int4*)(rowlist + (size_t)rr_ * FSLOTS);   \
        LA = lp_[0]; LB = lp_[1]; LC = lp_[2]; LD = lp_[3];                \
      }                                                                    \
    }                                                                      \
  }

#define PREF(cc, BND, RC, LA, LB, LC, LD)                                  \
  if ((cc) < nch) {                                                        \
    int r_ = (cc) * 64 + lane;                                             \
    int rr_ = r_ < n ? r_ : n - 1;                                         \
    BND = D1[rr_];                                                         \
    RC = rowcnt[rr_];                                                      \
    const int4* lp_ = (const int4*)(rowlist + (size_t)rr_ * FSLOTS);       \
    LA = lp_[0]; LB = lp_[1]; LC = lp_[2]; LD = lp_[3];                    \
  }

#define SCAN_BODY(NCH_)                                                    \
  int nch = (NCH_);                                                        \
  for (int w = lane; w < 128; w += 64) {                                   \
    u64 m = 0;                                                             \
    if (w < nw) {                                                          \
      long long hi = (long long)(w + 1) * 64;                              \
      m = (hi <= n) ? ~0ULL                                                \
                    : ((n > (long long)w * 64)                             \
                           ? (((u64)1 << (n - w * 64)) - 1) : 0ULL);       \
    }                                                                      \
    live[w] = m;                                                           \
  }                                                                        \
  u64 b0 = 0, b1 = 0, b2 = 0, b3 = 0;                                      \
  int rc0 = 0, rc1 = 0, rc2 = 0, rc3 = 0;                                  \
  int4 l00 = {0,0,0,0}, l01 = {0,0,0,0}, l02 = {0,0,0,0}, l03 = {0,0,0,0}; \
  int4 l10 = {0,0,0,0}, l11 = {0,0,0,0}, l12 = {0,0,0,0}, l13 = {0,0,0,0}; \
  int4 l20 = {0,0,0,0}, l21 = {0,0,0,0}, l22 = {0,0,0,0}, l23 = {0,0,0,0}; \
  int4 l30 = {0,0,0,0}, l31 = {0,0,0,0}, l32 = {0,0,0,0}, l33 = {0,0,0,0}; \
  PREF(0, b0, rc0, l00, l01, l02, l03)                                     \
  PREF(1, b1, rc1, l10, l11, l12, l13)                                     \
  PREF(2, b2, rc2, l20, l21, l22, l23)                                     \
  PREF(3, b3, rc3, l30, l31, l32, l33)                                     \
  int out = 0;                                                             \
  for (int kk = 0; kk < nch && out < maxp; kk += 4) {                      \
    CHUNK(kk + 0, b0, rc0, l00, l01, l02, l03)                             \
    CHUNK(kk + 1, b1, rc1, l10, l11, l12, l13)                             \
    CHUNK(kk + 2, b2, rc2, l20, l21, l22, l23)                             \
    CHUNK(kk + 3, b3, rc3, l30, l31, l32, l33)                             \
  }

// wave-scoped IoU tile (no block barrier; same-wave LDS ops are in-order)
__device__ __forceinline__ void do_tile(int wx, int ry, int lane,
                                        const float4* sb4, float4* cb,
                                        float* cbar, int n, float th,
                                        u64* M, u64* D1, int* rowcnt,
                                        int* rowlist, int nw) {
  int col0 = wx * 64;
  int cj = col0 + lane;
  int cjc = cj < n ? cj : n - 1;
  {
    float4 b4 = sb4[cjc];
    cb[lane] = b4;
    cbar[lane] = __fmul_rn(__fsub_rn(b4.z, b4.x), __fsub_rn(b4.w, b4.y));
  }
  int row = ry * 64 + lane;
  if (row >= n) return;
  float4 r4 = sb4[row];
  float rarea = __fmul_rn(__fsub_rn(r4.z, r4.x), __fsub_rn(r4.w, r4.y));
  u64 w = 0;
#pragma unroll 8
  for (int j = 0; j < 64; ++j) {
    float4 c4 = cb[j];
    float ix1 = fmaxf(r4.x, c4.x);
    float iy1 = fmaxf(r4.y, c4.y);
    float ix2 = fminf(r4.z, c4.z);
    float iy2 = fminf(r4.w, c4.w);
    float iw = fmaxf(__fsub_rn(ix2, ix1), 0.0f);
    float ih = fmaxf(__fsub_rn(iy2, iy1), 0.0f);
    float inter = __fmul_rn(iw, ih);
    float denom = __fadd_rn(__fsub_rn(__fadd_rn(rarea, cbar[j]), inter), 1e-12f);
    float iou = __fdiv_rn(inter, denom);
    int col = col0 + j;
    bool sup = (col > row) && (col < n) && (iou > th);
    w |= ((u64)sup) << j;
  }
  M[(size_t)row * nw + wx] = w;
  if (wx == ry) D1[row] = w;
  int pcw = (int)__popcll(w);
  if (pcw) {
    int base = atomicAdd(&rowcnt[row], pcw);
    u64 w2 = w;
    int k = 0;
    while (w2) {
      int j = (int)__builtin_ctzll(w2);
      w2 &= w2 - 1;
      int idx = base + k;
      if (idx < FSLOTS) rowlist[(size_t)row * FSLOTS + idx] = col0 + j;
      ++k;
    }
  }
}

// tri-index decode: u -> (wx, ry), ry <= wx
__device__ __forceinline__ void tri_decode(int u, int* wxo, int* ryo) {
  int w = (int)((sqrtf(8.0f * u + 1.0f) - 1.0f) * 0.5f);
  while ((w + 1) * (w + 2) / 2 <= u) ++w;
  while (w * (w + 1) / 2 > u) --w;
  *wxo = w;
  *ryo = u - w * (w + 1) / 2;
}

// ---------------- K1: rank + scatter + rowcnt zero + flags zero ----------------
__global__ __launch_bounds__(256)
void k_prep(const float* __restrict__ preds, int n,
            float* __restrict__ sboxes, int* __restrict__ sidx,
            int* __restrict__ rowcnt, int* __restrict__ flags) {
  __shared__ float cs[8192];
  int t = threadIdx.x;
  int b = blockIdx.x;
  for (int j = t; j < n; j += 256) cs[j] = preds[j * 5 + 4];
  {
    int zi = b * 32 + t;
    if (t < 32 && zi < n) rowcnt[zi] = 0;
    if (b == 0) {   // deterministic barrier state each replay
      flags[t] = 0; flags[t + 256] = 0; flags[t + 512] = 0;
    }
  }
  __syncthreads();

  int row = b * 32 + (t >> 3);
  int sub = t & 7;
  int cw = (((n + 7) >> 3) + 3) & ~3;
  int cnt = 0;
  if (row < n) {
    float ci = cs[row];
    int start = sub * cw;
    int end = start + cw; if (end > n) end = n;
    const float4* cs4 = (const float4*)cs;
    int s4 = start >> 2, e4 = end >> 2;
    for (int j4 = s4; j4 < e4; ++j4) {
      float4 c4 = cs4[j4];
      int jb = j4 * 4;
      cnt += (c4.x > ci) || (c4.x == ci && (jb + 0) < row);
      cnt += (c4.y > ci) || (c4.y == ci && (jb + 1) < row);
      cnt += (c4.z > ci) || (c4.z == ci && (jb + 2) < row);
      cnt += (c4.w > ci) || (c4.w == ci && (jb + 3) < row);
    }
    for (int j = e4 * 4; j < end; ++j)
      cnt += (cs[j] > ci) || (cs[j] == ci && j < row);
  }
  cnt += __shfl_down(cnt, 4, 8);
  cnt += __shfl_down(cnt, 2, 8);
  cnt += __shfl_down(cnt, 1, 8);
  if (sub == 0 && row < n) {
    int pos = cnt;
    sboxes[pos * 4 + 0] = preds[row * 5 + 0];
    sboxes[pos * 4 + 1] = preds[row * 5 + 1];
    sboxes[pos * 4 + 2] = preds[row * 5 + 2];
    sboxes[pos * 4 + 3] = preds[row * 5 + 3];
    sidx[pos] = row;
  }
}

// ---------------- K2: mask producers (bids 1..loTri) + block0 scan+emit ----------------
// 64-thread blocks, __launch_bounds__(64,1): proven VGPR config for the scan
// ring (round 16/27). One-way flag wait only -> deadlock-free.
__global__ __launch_bounds__(64, 1)
void k_main(u64* __restrict__ M, u64* __restrict__ D1,
            int* __restrict__ rowcnt, int* __restrict__ rowlist,
            const float* __restrict__ preds, const float* __restrict__ thr_p,
            const float* __restrict__ sboxes, const int* __restrict__ sidx,
            int n, int nw, int maxp, int Rw, int loTri,
            int* __restrict__ flags, float* __restrict__ outp) {
  __shared__ u64 live[128];
  __shared__ int selL[1024];
  __shared__ float4 cb[64];
  __shared__ float cbar[64];
  int lane = threadIdx.x;        // 0..63, one wave per block
  int bid = blockIdx.x;
  const float4* sb4 = (const float4*)sboxes;

  if (bid != 0) {
    // producer: one mask tile, then release flag
    float th = *thr_p;
    int wx, ry;
    tri_decode(bid - 1, &wx, &ry);
    do_tile(wx, ry, lane, sb4, cb, cbar, n, th, M, D1, rowcnt, rowlist, nw);
    // wave-in-order: all 64 lanes' stores precede lane 0 reaching here
    if (lane == 0) {
      __threadfence();   // agent-scope release of M/D1/rowcnt/rowlist
      __hip_atomic_store(&flags[bid], 1, __ATOMIC_RELEASE,
                         __HIP_MEMORY_SCOPE_AGENT);
    }
    return;
  }

  // block 0: one-way barrier — lane covers flags[1+lane], [65+lane], ...
  for (int f = 1 + lane; f <= loTri; f += 64)
    while (__hip_atomic_load(&flags[f], __ATOMIC_ACQUIRE,
                             __HIP_MEMORY_SCOPE_AGENT) == 0) {}
  // wave-level convergence: ballot forces all lanes past their spins
  __builtin_amdgcn_wave_barrier();

  int* sel = selL;
  int nk;
  bool done;
  {
    SCAN_BODY(Rw)
    nk = (out < maxp) ? out : maxp;
    done = (out >= maxp || Rw >= nw);
  }

  if (!done) {
    // cold path (never taken on this data): finish triangle single-wave, rescan
    int totTri = (nw * (nw + 1)) / 2;
    float th = *thr_p;
    for (int u = loTri; u < totTri; ++u) {
      int wx, ry;
      tri_decode(u, &wx, &ry);
      do_tile(wx, ry, lane, sb4, cb, cbar, n, th, M, D1, rowcnt, rowlist, nw);
    }
    {
      SCAN_BODY(nw)
      nk = (out < maxp) ? out : maxp;
    }
  }

  // emit
  for (int k = lane; k < maxp; k += 64) {
    if (k < nk) {
      int p = selL[k];
      int orig = sidx[p];
#pragma unroll
      for (int q = 0; q < 5; ++q) outp[k * 5 + q] = preds[orig * 5 + q];
      outp[(size_t)maxp * 5 + k] = (float)orig;
    } else {
#pragma unroll
      for (int q = 0; q < 5; ++q) outp[k * 5 + q] = 0.0f;
      outp[(size_t)maxp * 5 + k] = -1.0f;
    }
  }
}

extern "C" void kernel_launch(void* const* d_in, const int* in_sizes, int n_in,
                              void* d_out, int out_size, void* d_ws, size_t ws_size,
                              hipStream_t stream) {
  const float* preds = (const float*)d_in[0];
  const float* thr   = (const float*)d_in[1];
  float* out = (float*)d_out;
  int n    = in_sizes[0] / 5;          // 8192
  int maxp = out_size / 6;             // 1000
  int nw   = (n + 63) / 64;            // 128
  int Rw   = (RCUT / 64 < nw) ? RCUT / 64 : nw;   // 32
  int loTri = (Rw * (Rw + 1)) / 2;     // 528

  char* ws = (char*)d_ws;
  u64* M = (u64*)ws;
  size_t off = (size_t)n * nw * sizeof(u64);                   // 8 MB
  u64* D1 = (u64*)(ws + off);  off += (size_t)n * sizeof(u64); // 64 KB
  float* sboxes = (float*)(ws + off);  off += (size_t)n * 4 * sizeof(float);
  int*   sidx   = (int*)(ws + off);    off += (size_t)n * sizeof(int);
  int*   rowcnt = (int*)(ws + off);    off += (size_t)n * sizeof(int);
  int*   rowlist= (int*)(ws + off);    off += (size_t)n * FSLOTS * sizeof(int);
  int*   flags  = (int*)(ws + off);

  hipLaunchKernelGGL(k_prep, dim3((n + 31) / 32), dim3(256), 0, stream,
                     preds, n, sboxes, sidx, rowcnt, flags);
  hipLaunchKernelGGL(k_main, dim3(loTri + 1), dim3(64), 0, stream,
                     M, D1, rowcnt, rowlist, preds, thr, sboxes, sidx,
                     n, nw, maxp, Rw, loTri, flags, out);
}

// Round 29
// 67.501 us; speedup vs baseline: 1.3497x; 1.3497x over previous
//
#include <hip/hip_runtime.h>

typedef unsigned long long u64;

#define FSLOTS 16   // per-row sparse column slots
#define RCUT 2048   // speculative scan prefix

// wave-uniform 64-bit broadcast from SGPR lane index b
__device__ __forceinline__ u64 bcast64(u64 v, int b) {
  unsigned lo = __builtin_amdgcn_readlane((unsigned)v, b);
  unsigned hi = __builtin_amdgcn_readlane((unsigned)(v >> 32), b);
  return ((u64)hi << 32) | lo;
}
__device__ __forceinline__ u64 sgpr64(u64 v) {
  unsigned lo = __builtin_amdgcn_readfirstlane((unsigned)v);
  unsigned hi = __builtin_amdgcn_readfirstlane((unsigned)(v >> 32));
  return ((u64)hi << 32) | lo;
}
__device__ __forceinline__ u64 wor64(u64 v) {
#pragma unroll
  for (int off = 32; off; off >>= 1) v |= __shfl_xor(v, off, 64);
  return v;
}

#define APPLYJ(JV, T)                                                      \
  if ((T) < lim_) {                                                        \
    int j_ = (JV);                                                         \
    atomicAnd(&live[j_ >> 6], ~((u64)1 << (j_ & 63)));                     \
  }

#define CHUNK(c, BND, RC, LA, LB, LC, LD)                                  \
  if (out < maxp && (c) < nch) {                                           \
    u64 rem_ = sgpr64(live[(c)]);                                          \
    if (rem_) {                                                            \
      u64 K_;                                                              \
      u64 my_ = ((rem_ >> lane) & 1) ? (BND) : 0;                          \
      u64 A_ = sgpr64(wor64(my_));                                         \
      u64 hot_ = rem_ & A_;                                                \
      if (!hot_) {                                                         \
        K_ = rem_;                                                         \
      } else {                                                             \
        u64 defK_ = rem_ & ~A_;                                            \
        u64 myk_ = ((defK_ >> lane) & 1) ? (BND) : 0;                      \
        u64 S_ = sgpr64(wor64(myk_));                                      \
        K_ = defK_;                                                        \
        while (hot_) {                                                     \
          int b_ = __builtin_amdgcn_readfirstlane(                         \
              (int)__builtin_ctzll(hot_));                                 \
          hot_ &= hot_ - 1;                                                \
          if (!((S_ >> b_) & 1)) {                                         \
            K_ |= (u64)1 << b_;                                            \
            S_ |= bcast64(BND, b_);                                        \
          }                                                                \
        }                                                                  \
      }                                                                    \
      int kc_ = (int)__popcll(K_);                                         \
      bool mine_ = (K_ >> lane) & 1;                                       \
      if (mine_) {                                                         \
        int pos_ = out + (int)__popcll(K_ & (((u64)1 << lane) - 1));       \
        if (pos_ < maxp) sel[pos_] = (c) * 64 + lane;                      \
      }                                                                    \
      out += kc_;                                                          \
      if (kc_ > 0 && out < maxp) {                                         \
        int lim_ = mine_ ? ((RC) < FSLOTS ? (RC) : FSLOTS) : 0;            \
        APPLYJ((LA).x, 0)  APPLYJ((LA).y, 1)                               \
        APPLYJ((LA).z, 2)  APPLYJ((LA).w, 3)                               \
        APPLYJ((LB).x, 4)  APPLYJ((LB).y, 5)                               \
        APPLYJ((LB).z, 6)  APPLYJ((LB).w, 7)                               \
        APPLYJ((LC).x, 8)  APPLYJ((LC).y, 9)                               \
        APPLYJ((LC).z, 10) APPLYJ((LC).w, 11)                              \
        APPLYJ((LD).x, 12) APPLYJ((LD).y, 13)                              \
        APPLYJ((LD).z, 14) APPLYJ((LD).w, 15)                              \
        u64 ovf_ = __ballot(mine_ && (RC) > FSLOTS);                       \
        while (ovf_) {                                                     \
          int l_ = (int)__builtin_ctzll(ovf_);                             \
          ovf_ &= ovf_ - 1;                                                \
          int r_ = (c) * 64 + l_;                                          \
          u64 v0_ = (2 * lane < nch)                                       \
                        ? M[(size_t)r_ * nw + 2 * lane] : 0ULL;            \
          u64 v1_ = (2 * lane + 1 < nch)                                   \
                        ? M[(size_t)r_ * nw + 2 * lane + 1] : 0ULL;        \
          live[2 * lane] &= ~v0_;                                          \
          live[2 * lane + 1] &= ~v1_;                                      \
        }                                                                  \
      }                                                                    \
    }                                                                      \
    {                                                                      \
      int cc_ = (c) + 4;                                                   \
      if (cc_ < nch) {                                                     \
        int r_ = cc_ * 64 + lane;                                          \
        int rr_ = r_ < n ? r_ : n - 1;                                     \
        BND = D1[rr_];                                                     \
        RC = rowcnt[rr_];                                                  \
        const int4* lp_ = (const int4*)(rowlist + (size_t)rr_ * FSLOTS);   \
        LA = lp_[0]; LB = lp_[1]; LC = lp_[2]; LD = lp_[3];                \
      }                                                                    \
    }                                                                      \
  }

#define PREF(cc, BND, RC, LA, LB, LC, LD)                                  \
  if ((cc) < nch) {                                                        \
    int r_ = (cc) * 64 + lane;                                             \
    int rr_ = r_ < n ? r_ : n - 1;                                         \
    BND = D1[rr_];                                                         \
    RC = rowcnt[rr_];                                                      \
    const int4* lp_ = (const int4*)(rowlist + (size_t)rr_ * FSLOTS);       \
    LA = lp_[0]; LB = lp_[1]; LC = lp_[2]; LD = lp_[3];                    \
  }

#define SCAN_BODY(NCH_)                                                    \
  int nch = (NCH_);                                                        \
  for (int w = lane; w < 128; w += 64) {                                   \
    u64 m = 0;                                                             \
    if (w < nw) {                                                          \
      long long hi = (long long)(w + 1) * 64;                              \
      m = (hi <= n) ? ~0ULL                                                \
                    : ((n > (long long)w * 64)                             \
                           ? (((u64)1 << (n - w * 64)) - 1) : 0ULL);       \
    }                                                                      \
    live[w] = m;                                                           \
  }                                                                        \
  u64 b0 = 0, b1 = 0, b2 = 0, b3 = 0;                                      \
  int rc0 = 0, rc1 = 0, rc2 = 0, rc3 = 0;                                  \
  int4 l00 = {0,0,0,0}, l01 = {0,0,0,0}, l02 = {0,0,0,0}, l03 = {0,0,0,0}; \
  int4 l10 = {0,0,0,0}, l11 = {0,0,0,0}, l12 = {0,0,0,0}, l13 = {0,0,0,0}; \
  int4 l20 = {0,0,0,0}, l21 = {0,0,0,0}, l22 = {0,0,0,0}, l23 = {0,0,0,0}; \
  int4 l30 = {0,0,0,0}, l31 = {0,0,0,0}, l32 = {0,0,0,0}, l33 = {0,0,0,0}; \
  PREF(0, b0, rc0, l00, l01, l02, l03)                                     \
  PREF(1, b1, rc1, l10, l11, l12, l13)                                     \
  PREF(2, b2, rc2, l20, l21, l22, l23)                                     \
  PREF(3, b3, rc3, l30, l31, l32, l33)                                     \
  int out = 0;                                                             \
  for (int kk = 0; kk < nch && out < maxp; kk += 4) {                      \
    CHUNK(kk + 0, b0, rc0, l00, l01, l02, l03)                             \
    CHUNK(kk + 1, b1, rc1, l10, l11, l12, l13)                             \
    CHUNK(kk + 2, b2, rc2, l20, l21, l22, l23)                             \
    CHUNK(kk + 3, b3, rc3, l30, l31, l32, l33)                             \
  }

// wave-scoped IoU tile (no block barrier; same-wave LDS ops are in-order)
__device__ __forceinline__ void do_tile(int wx, int ry, int lane,
                                        const float4* sb4, float4* cb,
                                        float* cbar, int n, float th,
                                        u64* M, u64* D1, int* rowcnt,
                                        int* rowlist, int nw) {
  int col0 = wx * 64;
  int cj = col0 + lane;
  int cjc = cj < n ? cj : n - 1;
  {
    float4 b4 = sb4[cjc];
    cb[lane] = b4;
    cbar[lane] = __fmul_rn(__fsub_rn(b4.z, b4.x), __fsub_rn(b4.w, b4.y));
  }
  int row = ry * 64 + lane;
  if (row >= n) return;
  float4 r4 = sb4[row];
  float rarea = __fmul_rn(__fsub_rn(r4.z, r4.x), __fsub_rn(r4.w, r4.y));
  u64 w = 0;
#pragma unroll 8
  for (int j = 0; j < 64; ++j) {
    float4 c4 = cb[j];
    float ix1 = fmaxf(r4.x, c4.x);
    float iy1 = fmaxf(r4.y, c4.y);
    float ix2 = fminf(r4.z, c4.z);
    float iy2 = fminf(r4.w, c4.w);
    float iw = fmaxf(__fsub_rn(ix2, ix1), 0.0f);
    float ih = fmaxf(__fsub_rn(iy2, iy1), 0.0f);
    float inter = __fmul_rn(iw, ih);
    float denom = __fadd_rn(__fsub_rn(__fadd_rn(rarea, cbar[j]), inter), 1e-12f);
    float iou = __fdiv_rn(inter, denom);
    int col = col0 + j;
    bool sup = (col > row) && (col < n) && (iou > th);
    w |= ((u64)sup) << j;
  }
  M[(size_t)row * nw + wx] = w;
  if (wx == ry) D1[row] = w;
  int pcw = (int)__popcll(w);
  if (pcw) {
    int base = atomicAdd(&rowcnt[row], pcw);
    u64 w2 = w;
    int k = 0;
    while (w2) {
      int j = (int)__builtin_ctzll(w2);
      w2 &= w2 - 1;
      int idx = base + k;
      if (idx < FSLOTS) rowlist[(size_t)row * FSLOTS + idx] = col0 + j;
      ++k;
    }
  }
}

// tri-index decode: u -> (wx, ry), ry <= wx
__device__ __forceinline__ void tri_decode(int u, int* wxo, int* ryo) {
  int w = (int)((sqrtf(8.0f * u + 1.0f) - 1.0f) * 0.5f);
  while ((w + 1) * (w + 2) / 2 <= u) ++w;
  while (w * (w + 1) / 2 > u) --w;
  *wxo = w;
  *ryo = u - w * (w + 1) / 2;
}

// ---------------- K1: fused stable rank + scatter + rowcnt zero ----------------
__global__ __launch_bounds__(256)
void k_rank(const float* __restrict__ preds, int n,
            float* __restrict__ sboxes, int* __restrict__ sidx,
            int* __restrict__ rowcnt) {
  __shared__ float cs[8192];
  int t = threadIdx.x;
  int b = blockIdx.x;
  for (int j = t; j < n; j += 256) cs[j] = preds[j * 5 + 4];
  {
    int zi = b * 32 + t;
    if (t < 32 && zi < n) rowcnt[zi] = 0;
  }
  __syncthreads();

  int row = b * 32 + (t >> 3);
  int sub = t & 7;
  int cw = (((n + 7) >> 3) + 3) & ~3;
  int cnt = 0;
  if (row < n) {
    float ci = cs[row];
    int start = sub * cw;
    int end = start + cw; if (end > n) end = n;
    const float4* cs4 = (const float4*)cs;
    int s4 = start >> 2, e4 = end >> 2;
    for (int j4 = s4; j4 < e4; ++j4) {
      float4 c4 = cs4[j4];
      int jb = j4 * 4;
      cnt += (c4.x > ci) || (c4.x == ci && (jb + 0) < row);
      cnt += (c4.y > ci) || (c4.y == ci && (jb + 1) < row);
      cnt += (c4.z > ci) || (c4.z == ci && (jb + 2) < row);
      cnt += (c4.w > ci) || (c4.w == ci && (jb + 3) < row);
    }
    for (int j = e4 * 4; j < end; ++j)
      cnt += (cs[j] > ci) || (cs[j] == ci && j < row);
  }
  cnt += __shfl_down(cnt, 4, 8);
  cnt += __shfl_down(cnt, 2, 8);
  cnt += __shfl_down(cnt, 1, 8);
  if (sub == 0 && row < n) {
    int pos = cnt;
    sboxes[pos * 4 + 0] = preds[row * 5 + 0];
    sboxes[pos * 4 + 1] = preds[row * 5 + 1];
    sboxes[pos * 4 + 2] = preds[row * 5 + 2];
    sboxes[pos * 4 + 3] = preds[row * 5 + 3];
    sidx[pos] = row;
  }
}

// ---------------- K2: lo-corner mask tiles (packed 1D, 1 wave/block) ----------------
__global__ __launch_bounds__(64)
void k_mask_lo(const float* __restrict__ sboxes, int n,
               const float* __restrict__ thr_p,
               u64* __restrict__ M, u64* __restrict__ D1,
               int* __restrict__ rowcnt, int* __restrict__ rowlist, int nw) {
  __shared__ float4 cb[64];
  __shared__ float cbar[64];
  int wx, ry;
  tri_decode(blockIdx.x, &wx, &ry);
  do_tile(wx, ry, threadIdx.x, (const float4*)sboxes, cb, cbar, n, *thr_p,
          M, D1, rowcnt, rowlist, nw);
}

// ---------------- K3: finish = try-scan + (cold: rest of mask + rescan) + emit ----------------
__global__ __launch_bounds__(256, 1)
void k_finish(u64* __restrict__ M, u64* __restrict__ D1,
              int* __restrict__ rowcnt, int* __restrict__ rowlist,
              const float* __restrict__ preds, const float* __restrict__ thr_p,
              const float* __restrict__ sboxes, const int* __restrict__ sidx,
              int n, int nw, int maxp, int Rw,
              int* __restrict__ sel, float* __restrict__ outp) {
  __shared__ u64 live[128];
  __shared__ float4 cbw[4][64];
  __shared__ float cbarw[4][64];
  __shared__ int nk_s, done_s;
  int t = threadIdx.x;
  int wid = t >> 6;

  // phase T: speculative try-scan (wave 0)
  if (t < 64) {
    int lane = t;
    SCAN_BODY(Rw)
    if (lane == 0) {
      nk_s = (out < maxp) ? out : maxp;
      done_s = (out >= maxp || Rw >= nw) ? 1 : 0;
    }
  }
  __syncthreads();

  if (!done_s) {
    // cold path: compute the remaining tiles with all 4 waves, then rescan.
    int loTri = (Rw * (Rw + 1)) / 2;
    int totTri = (nw * (nw + 1)) / 2;
    float th = *thr_p;
    const float4* sb4 = (const float4*)sboxes;
    for (int u = loTri + wid; u < totTri; u += 4) {
      int wx, ry;
      tri_decode(u, &wx, &ry);
      do_tile(wx, ry, t & 63, sb4, cbw[wid], cbarw[wid], n, th,
              M, D1, rowcnt, rowlist, nw);
    }
    __threadfence();
    __syncthreads();
    if (t < 64) {
      int lane = t;
      SCAN_BODY(nw)
      if (lane == 0) nk_s = (out < maxp) ? out : maxp;
    }
    __syncthreads();
  }

  // phase E: emit
  int nk = nk_s;
  for (int k = t; k < maxp; k += 256) {
    if (k < nk) {
      int p = sel[k];
      int orig = sidx[p];
#pragma unroll
      for (int q = 0; q < 5; ++q) outp[k * 5 + q] = preds[orig * 5 + q];
      outp[(size_t)maxp * 5 + k] = (float)orig;
    } else {
#pragma unroll
      for (int q = 0; q < 5; ++q) outp[k * 5 + q] = 0.0f;
      outp[(size_t)maxp * 5 + k] = -1.0f;
    }
  }
}

extern "C" void kernel_launch(void* const* d_in, const int* in_sizes, int n_in,
                              void* d_out, int out_size, void* d_ws, size_t ws_size,
                              hipStream_t stream) {
  const float* preds = (const float*)d_in[0];
  const float* thr   = (const float*)d_in[1];
  float* out = (float*)d_out;
  int n    = in_sizes[0] / 5;          // 8192
  int maxp = out_size / 6;             // 1000
  int nw   = (n + 63) / 64;            // 128
  int Rw   = (RCUT / 64 < nw) ? RCUT / 64 : nw;   // 32
  int loTri = (Rw * (Rw + 1)) / 2;     // 528

  char* ws = (char*)d_ws;
  u64* M = (u64*)ws;
  size_t off = (size_t)n * nw * sizeof(u64);                   // 8 MB
  u64* D1 = (u64*)(ws + off);  off += (size_t)n * sizeof(u64); // 64 KB
  float* sboxes = (float*)(ws + off);  off += (size_t)n * 4 * sizeof(float);
  int*   sidx   = (int*)(ws + off);    off += (size_t)n * sizeof(int);
  int*   sel    = (int*)(ws + off);    off += (size_t)maxp * sizeof(int);
  int*   rowcnt = (int*)(ws + off);    off += (size_t)n * sizeof(int);
  int*   rowlist= (int*)(ws + off);

  hipLaunchKernelGGL(k_rank, dim3((n + 31) / 32), dim3(256), 0, stream,
                     preds, n, sboxes, sidx, rowcnt);
  hipLaunchKernelGGL(k_mask_lo, dim3(loTri), dim3(64), 0, stream,
                     sboxes, n, thr, M, D1, rowcnt, rowlist, nw);
  hipLaunchKernelGGL(k_finish, dim3(1), dim3(256), 0, stream,
                     M, D1, rowcnt, rowlist, preds, thr, sboxes, sidx,
                     n, nw, maxp, Rw, sel, out);
}